// Round 12
// baseline (68.182 us; speedup 1.0000x reference)
//
#include <hip/hip_runtime.h>
#include <hip/hip_bf16.h>
#include <stdint.h>

typedef __attribute__((ext_vector_type(4))) float f32x4;
typedef __attribute__((ext_vector_type(8))) short bf16x8;

#define NCH 21
#define NROW 256
#define DIM 4096
#define BK 128     // K-slab per iter
#define LDSS2 132  // row stride in ushorts (264B; 66 dwords = 2 mod 32 -> ~2-way, free)
#define NTILE 10   // upper-triangle 64x64 tiles of the 256x256 Gram

__device__ const int g_TI[NTILE] = {0, 0, 0, 0, 1, 1, 1, 2, 2, 3};
__device__ const int g_TJ[NTILE] = {0, 1, 2, 3, 1, 2, 3, 2, 3, 3};

__device__ __forceinline__ uint32_t pack_bf2(float x, float y) {
  __hip_bfloat162 h = __float22bfloat162_rn(float2{x, y});  // v_cvt_pk_bf16_f32
  union { __hip_bfloat162 h; uint32_t u; } c;
  c.h = h;
  return c.u;
}

// ---------------------------------------------------------------------------
// Pair-merged partial Gram with CHANNEL-SPREAD staging:
// one wave load-inst = 2 rows x 512B CONTIGUOUS (4 cache lines -> 4 L2
// channels), vs the old 8-rows x 256B pattern whose 344064B row stride
// (2688 lines = 0 mod 16) aliased every load to ~2 channels.
// Per (ch,ks) group, 3 blocks of 512 threads: bt0=rows(0..127)^2 (stage 1
// panel), bt1=rows(128..255)^2, bt2=off-diag (stage both panels, B staged
// in a 2nd sub-phase reusing the same stage registers).
// BK=128 -> 4 iters at P=8; 2 lgkm-only barriers/iter; never vmcnt(0).
// ---------------------------------------------------------------------------
__global__ __launch_bounds__(512, 4) void gram_kernel(
    const float* __restrict__ src, const float* __restrict__ tgt,
    float* __restrict__ Gp, int kshift, int kchunk) {
  const int P = 1 << kshift;
  const int NG = NCH << kshift;          // number of (ch,ks) groups
  const int q = NG >> 3, r8 = NG & 7;    // groups per XCD
  const int x = blockIdx.x & 7;          // XCD id (empirical round-robin)
  const int slot = blockIdx.x >> 3;
  const int cnt = q + (x < r8 ? 1 : 0);
  if (slot >= cnt * 3) return;           // padded grid tail (uniform exit)
  const int gbase = (x < r8) ? x * (q + 1) : r8 * (q + 1) + (x - r8) * q;
  const int gi = slot / 3;
  const int bt = slot - gi * 3;
  const int g = gbase + gi;
  const int ch = g >> kshift;
  const int ks = g & (P - 1);
  const int kbase = ks * kchunk;
  const int row_base = (bt == 1) ? 128 : 0;
  const int col_base = (bt == 0) ? 0 : 128;
  const bool isdiag = (bt != 2);
  const int tid = threadIdx.x;
  const int lane = tid & 63;
  const int w = tid >> 6;                // wave 0..7

  __shared__ __attribute__((aligned(16))) ushort As[128 * LDSS2];
  __shared__ __attribute__((aligned(16))) ushort Bs[128 * LDSS2];

  f32x4 acc[2][4];
#pragma unroll
  for (int m = 0; m < 2; ++m)
#pragma unroll
    for (int n = 0; n < 4; ++n)
      acc[m][n] = (f32x4){0.f, 0.f, 0.f, 0.f};

  const int wr = (w >> 1) * 32;    // 0,32,64,96
  const int wc = (w & 1) * 64;     // 0,64

  // staging geometry: wave w stages rows w*16 .. w*16+15 of the 128-row panel;
  // load-inst p covers rows w*16+2p and w*16+2p+1 (subrow = lane>>5), each
  // 512B contiguous: float offset (lane&31)*4 within the 128-float slab.
  const int subrow = lane >> 5;
  const int kf = (lane & 31) * 4;            // float offset in slab
  const float* Ab = row_base ? tgt : src;
  const float* Bb = col_base ? tgt : src;
  // per-inst base pointers (row = w*16 + 2p + subrow)
  const float* apr[8];
  const float* bpr[8];
#pragma unroll
  for (int p = 0; p < 8; ++p) {
    const int row = w * 16 + 2 * p + subrow;
    apr[p] = Ab + ((size_t)row * NCH + ch) * DIM + kbase + kf;
    bpr[p] = Bb + ((size_t)row * NCH + ch) * DIM + kbase + kf;
  }
  // LDS write address (ushort index) for inst p: row*LDSS2 + kf
  const int lw0 = (w * 16 + subrow) * LDSS2 + kf;

  const int nk = kchunk / BK;  // 4 at P=8

  for (int it = 0; it < nk; ++it) {
    const int ko = it * BK;
    // ---- stage A panel ----
    f32x4 v[8];
#pragma unroll
    for (int p = 0; p < 8; ++p) v[p] = *reinterpret_cast<const f32x4*>(apr[p] + ko);
#pragma unroll
    for (int p = 0; p < 8; ++p) {
      uint2 wv;
      wv.x = pack_bf2(v[p].x, v[p].y);
      wv.y = pack_bf2(v[p].z, v[p].w);
      *reinterpret_cast<uint2*>(&As[lw0 + 2 * p * LDSS2]) = wv;
    }
    // ---- stage B panel (off-diag only), reusing the same regs ----
    if (!isdiag) {
#pragma unroll
      for (int p = 0; p < 8; ++p) v[p] = *reinterpret_cast<const f32x4*>(bpr[p] + ko);
#pragma unroll
      for (int p = 0; p < 8; ++p) {
        uint2 wv;
        wv.x = pack_bf2(v[p].x, v[p].y);
        wv.y = pack_bf2(v[p].z, v[p].w);
        *reinterpret_cast<uint2*>(&Bs[lw0 + 2 * p * LDSS2]) = wv;
      }
    }
    // writes visible; never drain vmcnt here
    asm volatile("s_waitcnt lgkmcnt(0)" ::: "memory");
    __builtin_amdgcn_s_barrier();
    asm volatile("" ::: "memory");

    const ushort* Bsrc = isdiag ? As : Bs;
#pragma unroll
    for (int kk = 0; kk < 4; ++kk) {
      const int kb = kk * 32 + (lane >> 4) * 8;
      bf16x8 a[2], b[4];
#pragma unroll
      for (int m = 0; m < 2; ++m)
        a[m] = *reinterpret_cast<const bf16x8*>(
            &As[(wr + m * 16 + (lane & 15)) * LDSS2 + kb]);
#pragma unroll
      for (int n = 0; n < 4; ++n)
        b[n] = *reinterpret_cast<const bf16x8*>(
            &Bsrc[(wc + n * 16 + (lane & 15)) * LDSS2 + kb]);
#pragma unroll
      for (int m = 0; m < 2; ++m)
#pragma unroll
        for (int n = 0; n < 4; ++n)
          acc[m][n] = __builtin_amdgcn_mfma_f32_16x16x32_bf16(a[m], b[n],
                                                              acc[m][n], 0, 0, 0);
    }
    // reads of this iter's LDS done before next iter's writes
    asm volatile("s_waitcnt lgkmcnt(0)" ::: "memory");
    __builtin_amdgcn_s_barrier();
    asm volatile("" ::: "memory");
  }

  // C/D layout (m89): col = lane&15, row = (lane>>4)*4 + reg. Skip mirrors.
  float* gp = Gp + (size_t)(ch * P + ks) * (NROW * NROW);
#pragma unroll
  for (int m = 0; m < 2; ++m)
#pragma unroll
    for (int n = 0; n < 4; ++n) {
      const int grow = row_base + wr + m * 16 + ((lane >> 4) << 2);
      const int gcol = col_base + wc + n * 16 + (lane & 15);
      if ((grow >> 6) > (gcol >> 6)) continue;  // lower-tri mirror: not stored
#pragma unroll
      for (int j = 0; j < 4; ++j)
        gp[(size_t)(grow + j) * NROW + gcol] = acc[m][n][j];
    }
}

// ---------------------------------------------------------------------------
__device__ __forceinline__ float block_sum256(float v, float* sm) {
#pragma unroll
  for (int o = 32; o > 0; o >>= 1) v += __shfl_down(v, o, 64);
  const int lane = threadIdx.x & 63;
  const int wv = threadIdx.x >> 6;
  if (lane == 0) sm[wv] = v;
  __syncthreads();
  float r = 0.f;
  if (threadIdx.x == 0) r = sm[0] + sm[1] + sm[2] + sm[3];
  __syncthreads();
  return r;  // valid on thread 0
}

// ---------------------------------------------------------------------------
// Fold K-split partials for one (ch,tile) AND produce tile sum + diag trace.
__global__ __launch_bounds__(256) void foldsum_kernel(
    const f32x4* __restrict__ Gp, f32x4* __restrict__ Gf,
    float* __restrict__ sums, int P) {
  const int t = blockIdx.x;
  const int ch = blockIdx.y;
  const int ti = g_TI[t], tj = g_TJ[t];
  const bool isdiag = (ti == tj);
  const int tid = threadIdx.x;
  float s = 0.f, tr = 0.f;
#pragma unroll
  for (int i = 0; i < 4; ++i) {
    const int idx4 = tid * 4 + i;
    const int rrow = idx4 >> 4;       // 0..63
    const int c4 = idx4 & 15;         // 0..15
    const int base_v = (ti * 64 + rrow) * 64 + tj * 16 + c4;
    f32x4 v = Gp[(size_t)(ch * P) * 16384 + base_v];
    for (int p = 1; p < P; ++p) v += Gp[(size_t)(ch * P + p) * 16384 + base_v];
    Gf[(size_t)ch * 16384 + base_v] = v;
    s += (v.x + v.y) + (v.z + v.w);
    if (isdiag) {
      const int cb = c4 * 4;
#pragma unroll
      for (int e = 0; e < 4; ++e)
        if (cb + e == rrow) tr += v[e];
    }
  }
  __shared__ float sm[4];
  float sG = block_sum256(s, sm);
  float sT = block_sum256(tr, sm);
  if (tid == 0) {
    sums[ch * 20 + t] = sG;
    if (isdiag) sums[ch * 20 + 10 + ti] = sT;
  }
}

// ---------------------------------------------------------------------------
// per (tile, ch): w * sign * sum over tile of sum_a exp(-L2/(bw*2^a)).
__global__ __launch_bounds__(256) void mmd_kernel(const float* __restrict__ Gf,
                                                  const float* __restrict__ sums,
                                                  float* __restrict__ partial) {
  const int t = blockIdx.x;
  const int ch = blockIdx.y;
  const int ti = g_TI[t], tj = g_TJ[t];
  const int tid = threadIdx.x;
  const float* gg = Gf + (size_t)ch * (NROW * NROW);

  const float* sc = sums + ch * 20;
  float sumG = 0.f;
#pragma unroll
  for (int k = 0; k < NTILE; ++k)
    sumG += (g_TI[k] == g_TJ[k] ? 1.f : 2.f) * sc[k];
  const float trace = (sc[10] + sc[11]) + (sc[12] + sc[13]);
  const float sumL2 = 2.f * NROW * trace - 2.f * sumG;
  const float bw = sumL2 / (float)(NROW * NROW - NROW) * 0.25f;
  float inv[5];
#pragma unroll
  for (int a = 0; a < 5; ++a) inv[a] = -1.f / (bw * (float)(1 << a));

  __shared__ float dA[64], dB[64];
  if (tid < 64) dA[tid] = gg[(size_t)(ti * 64 + tid) * (NROW + 1)];
  else if (tid < 128) dB[tid - 64] = gg[(size_t)(tj * 64 + (tid - 64)) * (NROW + 1)];
  __syncthreads();

  const int col = tid & 63;
  const int qq = tid >> 6;
  const float dj = dB[col];
  float acc = 0.f;
#pragma unroll 4
  for (int it = 0; it < 16; ++it) {
    const int r = it * 4 + qq;
    const float L2 = dA[r] + dj - 2.f * gg[(size_t)(ti * 64 + r) * NROW + tj * 64 + col];
    float kv = 0.f;
#pragma unroll
    for (int a = 0; a < 5; ++a) kv += __expf(L2 * inv[a]);
    acc += kv;
  }
  __shared__ float sm[4];
  float tot = block_sum256(acc, sm);
  if (tid == 0) {
    float wgt = (ti == tj) ? 1.f : 2.f;                  // off-diag mirror
    float sgn = ((ti >= 2) == (tj >= 2)) ? 1.f : -1.f;   // XX/YY + , XY/YX -
    partial[ch * NTILE + t] = tot * wgt * sgn;
  }
}

__global__ __launch_bounds__(256) void final_kernel(const float* __restrict__ partial,
                                                    float* __restrict__ out) {
  const int tid = threadIdx.x;
  float v = (tid < NCH * NTILE) ? partial[tid] : 0.f;
  __shared__ float sm[4];
  float tot = block_sum256(v, sm);
  if (tid == 0) out[0] = tot * (1.f / (NCH * 128.f * 128.f));
}

// ---------------------------------------------------------------------------
extern "C" void kernel_launch(void* const* d_in, const int* in_sizes, int n_in,
                              void* d_out, int out_size, void* d_ws, size_t ws_size,
                              hipStream_t stream) {
  const float* src = (const float*)d_in[0];
  const float* tgt = (const float*)d_in[1];
  float* out = (float*)d_out;
  const size_t GSZ = (size_t)NROW * NROW;  // 65536

  // P capped at 8 (P=16 blew up foldsum, R10).
  int kshift = 0;
  if (ws_size >= (NCH * 9 * GSZ + 512) * sizeof(float)) kshift = 3;
  else if (ws_size >= (NCH * 5 * GSZ + 512) * sizeof(float)) kshift = 2;
  else if (ws_size >= (NCH * 3 * GSZ + 512) * sizeof(float)) kshift = 1;
  const int P = 1 << kshift;

  float* Gp = (float*)d_ws;
  float* Gf = (P > 1) ? Gp + (size_t)NCH * P * GSZ : Gp;  // P==1: alias
  float* sums = Gf + (size_t)NCH * GSZ;                   // NCH*20
  float* partial = sums + NCH * 20;                       // NCH*10

  const int NG = NCH * P;
  const int q = NG / 8, r8 = NG % 8;
  const int grid = 8 * (q + (r8 ? 1 : 0)) * 3;

  gram_kernel<<<dim3(grid), 512, 0, stream>>>(src, tgt, Gp, kshift, DIM >> kshift);
  foldsum_kernel<<<dim3(NTILE, NCH), 256, 0, stream>>>((const f32x4*)Gp,
                                                       (f32x4*)Gf, sums, P);
  mmd_kernel<<<dim3(NTILE, NCH), 256, 0, stream>>>(Gf, sums, partial);
  final_kernel<<<1, 256, 0, stream>>>(partial, out);
}

// Round 13
// 48.327 us; speedup vs baseline: 1.4108x; 1.4108x over previous
//
#include <hip/hip_runtime.h>
#include <hip/hip_bf16.h>
#include <stdint.h>

typedef __attribute__((ext_vector_type(4))) float f32x4;
typedef __attribute__((ext_vector_type(8))) short bf16x8;

#define NCH 21
#define NROW 256
#define DIM 4096
#define BK 64
#define NTILE 10  // upper-triangle 64x64 tiles of the 256x256 Gram

__device__ const int g_TI[NTILE] = {0, 0, 0, 0, 1, 1, 1, 2, 2, 3};
__device__ const int g_TJ[NTILE] = {0, 1, 2, 3, 1, 2, 3, 2, 3, 3};

typedef const __attribute__((address_space(1))) uint32_t gas_u32;
typedef __attribute__((address_space(3))) uint32_t las_u32;

__device__ __forceinline__ uint32_t pack_bf2(float x, float y) {
  __hip_bfloat162 h = __float22bfloat162_rn(float2{x, y});  // v_cvt_pk_bf16_f32
  union { __hip_bfloat162 h; uint32_t u; } c;
  c.h = h;
  return c.u;
}

// LDS float-offset with st-style XOR swizzle: element (row, fcol) lives at
// chunk (fcol>>2)^(row&7) of row. 16 lanes reading 16 rows at same fcol ->
// 8 distinct 16B slots -> 2-way bank aliasing (free, m136).
__device__ __forceinline__ int lds_foff(int row, int fcol) {
  return row * 64 + ((((fcol >> 2) ^ (row & 7)) & 15) << 2);
}

// ---------------------------------------------------------------------------
// Pair-merged partial Gram with the m97 staging engine:
//   global_load_lds (16B/lane) stages f32 panels straight to LDS (no VGPR
//   round-trip, no pack at stage; Common-mistake #1 / m93->m97 lever).
//   gload_lds writes lane-linear, so the XOR swizzle is applied on BOTH
//   sides (rule #21): pre-swizzled per-lane GLOBAL source + same XOR on the
//   LDS read. f32->bf16 conversion (same RNE cvt_pk) moves to fragment-read.
// Groups/grid/tiling identical to R9: per (ch,ks) group 3 blocks of 512 thr
// (bt0 = rows(0..127)^2 one panel; bt1 = rows(128..255)^2; bt2 = off-diag,
// two panels), bijective XCD grouping, P=8, mirrors skipped at C-write.
// ---------------------------------------------------------------------------
__global__ __launch_bounds__(512, 4) void gram_kernel(
    const float* __restrict__ src, const float* __restrict__ tgt,
    float* __restrict__ Gp, int kshift, int kchunk) {
  const int P = 1 << kshift;
  const int NG = NCH << kshift;          // number of (ch,ks) groups
  const int q = NG >> 3, r8 = NG & 7;    // groups per XCD
  const int x = blockIdx.x & 7;          // XCD id (empirical round-robin)
  const int slot = blockIdx.x >> 3;
  const int cnt = q + (x < r8 ? 1 : 0);
  if (slot >= cnt * 3) return;           // padded grid tail (uniform exit)
  const int gbase = (x < r8) ? x * (q + 1) : r8 * (q + 1) + (x - r8) * q;
  const int gi = slot / 3;
  const int bt = slot - gi * 3;
  const int g = gbase + gi;
  const int ch = g >> kshift;
  const int ks = g & (P - 1);
  const int kbase = ks * kchunk;
  const int row_base = (bt == 1) ? 128 : 0;
  const int col_base = (bt == 0) ? 0 : 128;
  const bool isdiag = (bt != 2);
  const int tid = threadIdx.x;
  const int lane = tid & 63;
  const int wave = tid >> 6;             // 0..7

  __shared__ __attribute__((aligned(16))) float AsF[128 * 64];  // 32 KB
  __shared__ __attribute__((aligned(16))) float BsF[128 * 64];  // 32 KB

  f32x4 acc[2][4];
#pragma unroll
  for (int m = 0; m < 2; ++m)
#pragma unroll
    for (int n = 0; n < 4; ++n)
      acc[m][n] = (f32x4){0.f, 0.f, 0.f, 0.f};

  const int wr = (wave >> 1) * 32;    // 0,32,64,96
  const int wc = (wave & 1) * 64;     // 0,64

  // staging: panel = 128 rows x 64 f32 = 32KB = 4 insts x 512 thr x 16B.
  // inst i, thread tid -> 16B chunk id = i*512+tid: row = id>>4, c16 = id&15.
  // Source col chunk is pre-swizzled: c16 ^ (row&7)  (rule #21).
  const float* Ab = row_base ? tgt : src;
  const float* Bb = col_base ? tgt : src;
  const float* gA[4];
  const float* gB[4];
#pragma unroll
  for (int i = 0; i < 4; ++i) {
    const int id = i * 512 + tid;
    const int row = id >> 4;
    const int csw = ((id & 15) ^ (row & 7)) * 4;   // swizzled float col
    gA[i] = Ab + ((size_t)row * NCH + ch) * DIM + kbase + csw;
    gB[i] = Bb + ((size_t)row * NCH + ch) * DIM + kbase + csw;
  }

  const int nk = kchunk / BK;  // 8 at P=8

  for (int it = 0; it < nk; ++it) {
    const int ko = it * BK;
    // ---- async stage: global -> LDS direct, 16B per lane ----
#pragma unroll
    for (int i = 0; i < 4; ++i) {
      __builtin_amdgcn_global_load_lds(
          (gas_u32*)(const void*)(gA[i] + ko),
          (las_u32*)(void*)(AsF + i * 2048 + wave * 256), 16, 0, 0);
    }
    if (!isdiag) {
#pragma unroll
      for (int i = 0; i < 4; ++i) {
        __builtin_amdgcn_global_load_lds(
            (gas_u32*)(const void*)(gB[i] + ko),
            (las_u32*)(void*)(BsF + i * 2048 + wave * 256), 16, 0, 0);
      }
    }
    __syncthreads();  // drains vmcnt (gload_lds completion) + lgkm

    const float* Bsrc = isdiag ? AsF : BsF;
#pragma unroll
    for (int kk = 0; kk < 2; ++kk) {
      const int kf = kk * 32 + (lane >> 4) * 8;  // float col of 8-elem frag
      bf16x8 a[2], b[4];
#pragma unroll
      for (int m = 0; m < 2; ++m) {
        const int row = wr + m * 16 + (lane & 15);
        f32x4 x0 = *reinterpret_cast<const f32x4*>(&AsF[lds_foff(row, kf)]);
        f32x4 x1 = *reinterpret_cast<const f32x4*>(&AsF[lds_foff(row, kf + 4)]);
        union { bf16x8 v; uint32_t u[4]; } cv;
        cv.u[0] = pack_bf2(x0.x, x0.y);
        cv.u[1] = pack_bf2(x0.z, x0.w);
        cv.u[2] = pack_bf2(x1.x, x1.y);
        cv.u[3] = pack_bf2(x1.z, x1.w);
        a[m] = cv.v;
      }
#pragma unroll
      for (int n = 0; n < 4; ++n) {
        const int row = wc + n * 16 + (lane & 15);
        f32x4 x0 = *reinterpret_cast<const f32x4*>(&Bsrc[lds_foff(row, kf)]);
        f32x4 x1 = *reinterpret_cast<const f32x4*>(&Bsrc[lds_foff(row, kf + 4)]);
        union { bf16x8 v; uint32_t u[4]; } cv;
        cv.u[0] = pack_bf2(x0.x, x0.y);
        cv.u[1] = pack_bf2(x0.z, x0.w);
        cv.u[2] = pack_bf2(x1.x, x1.y);
        cv.u[3] = pack_bf2(x1.z, x1.w);
        b[n] = cv.v;
      }
#pragma unroll
      for (int m = 0; m < 2; ++m)
#pragma unroll
        for (int n = 0; n < 4; ++n)
          acc[m][n] = __builtin_amdgcn_mfma_f32_16x16x32_bf16(a[m], b[n],
                                                              acc[m][n], 0, 0, 0);
    }
    __syncthreads();  // LDS reads done before next iter's gload_lds overwrite
  }

  // C/D layout (m89): col = lane&15, row = (lane>>4)*4 + reg. Skip mirrors.
  float* gp = Gp + (size_t)(ch * P + ks) * (NROW * NROW);
#pragma unroll
  for (int m = 0; m < 2; ++m)
#pragma unroll
    for (int n = 0; n < 4; ++n) {
      const int grow = row_base + wr + m * 16 + ((lane >> 4) << 2);
      const int gcol = col_base + wc + n * 16 + (lane & 15);
      if ((grow >> 6) > (gcol >> 6)) continue;  // lower-tri mirror: not stored
#pragma unroll
      for (int j = 0; j < 4; ++j)
        gp[(size_t)(grow + j) * NROW + gcol] = acc[m][n][j];
    }
}

// ---------------------------------------------------------------------------
__device__ __forceinline__ float block_sum256(float v, float* sm) {
#pragma unroll
  for (int o = 32; o > 0; o >>= 1) v += __shfl_down(v, o, 64);
  const int lane = threadIdx.x & 63;
  const int wv = threadIdx.x >> 6;
  if (lane == 0) sm[wv] = v;
  __syncthreads();
  float r = 0.f;
  if (threadIdx.x == 0) r = sm[0] + sm[1] + sm[2] + sm[3];
  __syncthreads();
  return r;  // valid on thread 0
}

// ---------------------------------------------------------------------------
// Fold K-split partials for one (ch,tile) AND produce tile sum + diag trace.
__global__ __launch_bounds__(256) void foldsum_kernel(
    const f32x4* __restrict__ Gp, f32x4* __restrict__ Gf,
    float* __restrict__ sums, int P) {
  const int t = blockIdx.x;
  const int ch = blockIdx.y;
  const int ti = g_TI[t], tj = g_TJ[t];
  const bool isdiag = (ti == tj);
  const int tid = threadIdx.x;
  float s = 0.f, tr = 0.f;
#pragma unroll
  for (int i = 0; i < 4; ++i) {
    const int idx4 = tid * 4 + i;
    const int rrow = idx4 >> 4;       // 0..63
    const int c4 = idx4 & 15;         // 0..15
    const int base_v = (ti * 64 + rrow) * 64 + tj * 16 + c4;
    f32x4 v = Gp[(size_t)(ch * P) * 16384 + base_v];
    for (int p = 1; p < P; ++p) v += Gp[(size_t)(ch * P + p) * 16384 + base_v];
    Gf[(size_t)ch * 16384 + base_v] = v;
    s += (v.x + v.y) + (v.z + v.w);
    if (isdiag) {
      const int cb = c4 * 4;
#pragma unroll
      for (int e = 0; e < 4; ++e)
        if (cb + e == rrow) tr += v[e];
    }
  }
  __shared__ float sm[4];
  float sG = block_sum256(s, sm);
  float sT = block_sum256(tr, sm);
  if (tid == 0) {
    sums[ch * 20 + t] = sG;
    if (isdiag) sums[ch * 20 + 10 + ti] = sT;
  }
}

// ---------------------------------------------------------------------------
// per (tile, ch): w * sign * sum over tile of sum_a exp(-L2/(bw*2^a)).
__global__ __launch_bounds__(256) void mmd_kernel(const float* __restrict__ Gf,
                                                  const float* __restrict__ sums,
                                                  float* __restrict__ partial) {
  const int t = blockIdx.x;
  const int ch = blockIdx.y;
  const int ti = g_TI[t], tj = g_TJ[t];
  const int tid = threadIdx.x;
  const float* gg = Gf + (size_t)ch * (NROW * NROW);

  const float* sc = sums + ch * 20;
  float sumG = 0.f;
#pragma unroll
  for (int k = 0; k < NTILE; ++k)
    sumG += (g_TI[k] == g_TJ[k] ? 1.f : 2.f) * sc[k];
  const float trace = (sc[10] + sc[11]) + (sc[12] + sc[13]);
  const float sumL2 = 2.f * NROW * trace - 2.f * sumG;
  const float bw = sumL2 / (float)(NROW * NROW - NROW) * 0.25f;
  float inv[5];
#pragma unroll
  for (int a = 0; a < 5; ++a) inv[a] = -1.f / (bw * (float)(1 << a));

  __shared__ float dA[64], dB[64];
  if (tid < 64) dA[tid] = gg[(size_t)(ti * 64 + tid) * (NROW + 1)];
  else if (tid < 128) dB[tid - 64] = gg[(size_t)(tj * 64 + (tid - 64)) * (NROW + 1)];
  __syncthreads();

  const int col = tid & 63;
  const int qq = tid >> 6;
  const float dj = dB[col];
  float acc = 0.f;
#pragma unroll 4
  for (int it = 0; it < 16; ++it) {
    const int r = it * 4 + qq;
    const float L2 = dA[r] + dj - 2.f * gg[(size_t)(ti * 64 + r) * NROW + tj * 64 + col];
    float kv = 0.f;
#pragma unroll
    for (int a = 0; a < 5; ++a) kv += __expf(L2 * inv[a]);
    acc += kv;
  }
  __shared__ float sm[4];
  float tot = block_sum256(acc, sm);
  if (tid == 0) {
    float wgt = (ti == tj) ? 1.f : 2.f;                  // off-diag mirror
    float sgn = ((ti >= 2) == (tj >= 2)) ? 1.f : -1.f;   // XX/YY + , XY/YX -
    partial[ch * NTILE + t] = tot * wgt * sgn;
  }
}

__global__ __launch_bounds__(256) void final_kernel(const float* __restrict__ partial,
                                                    float* __restrict__ out) {
  const int tid = threadIdx.x;
  float v = (tid < NCH * NTILE) ? partial[tid] : 0.f;
  __shared__ float sm[4];
  float tot = block_sum256(v, sm);
  if (tid == 0) out[0] = tot * (1.f / (NCH * 128.f * 128.f));
}

// ---------------------------------------------------------------------------
extern "C" void kernel_launch(void* const* d_in, const int* in_sizes, int n_in,
                              void* d_out, int out_size, void* d_ws, size_t ws_size,
                              hipStream_t stream) {
  const float* src = (const float*)d_in[0];
  const float* tgt = (const float*)d_in[1];
  float* out = (float*)d_out;
  const size_t GSZ = (size_t)NROW * NROW;  // 65536

  // P capped at 8 (P=16 blew up foldsum, R10).
  int kshift = 0;
  if (ws_size >= (NCH * 9 * GSZ + 512) * sizeof(float)) kshift = 3;
  else if (ws_size >= (NCH * 5 * GSZ + 512) * sizeof(float)) kshift = 2;
  else if (ws_size >= (NCH * 3 * GSZ + 512) * sizeof(float)) kshift = 1;
  const int P = 1 << kshift;

  float* Gp = (float*)d_ws;
  float* Gf = (P > 1) ? Gp + (size_t)NCH * P * GSZ : Gp;  // P==1: alias
  float* sums = Gf + (size_t)NCH * GSZ;                   // NCH*20
  float* partial = sums + NCH * 20;                       // NCH*10

  const int NG = NCH * P;
  const int q = NG / 8, r8 = NG % 8;
  const int grid = 8 * (q + (r8 ? 1 : 0)) * 3;

  gram_kernel<<<dim3(grid), 512, 0, stream>>>(src, tgt, Gp, kshift, DIM >> kshift);
  foldsum_kernel<<<dim3(NTILE, NCH), 256, 0, stream>>>((const f32x4*)Gp,
                                                       (f32x4*)Gf, sums, P);
  mmd_kernel<<<dim3(NTILE, NCH), 256, 0, stream>>>(Gf, sums, partial);
  final_kernel<<<1, 256, 0, stream>>>(partial, out);
}

// Round 14
// 44.150 us; speedup vs baseline: 1.5443x; 1.0946x over previous
//
#include <hip/hip_runtime.h>
#include <hip/hip_bf16.h>
#include <stdint.h>

typedef __attribute__((ext_vector_type(4))) float f32x4;
typedef __attribute__((ext_vector_type(8))) short bf16x8;

#define NCH 21
#define NROW 256
#define DIM 4096
#define BK 64
#define NTILE 10  // upper-triangle 64x64 tiles of the 256x256 Gram

__device__ const int g_TI[NTILE] = {0, 0, 0, 0, 1, 1, 1, 2, 2, 3};
__device__ const int g_TJ[NTILE] = {0, 1, 2, 3, 1, 2, 3, 2, 3, 3};

__device__ __forceinline__ uint32_t pack_bf2(float x, float y) {
  __hip_bfloat162 h = __float22bfloat162_rn(float2{x, y});  // v_cvt_pk_bf16_f32
  union { __hip_bfloat162 h; uint32_t u; } c;
  c.h = h;
  return c.u;
}

// ---------------------------------------------------------------------------
// One 1024-thread block per (ch,ks) group: stage the FULL 256-row x 64-col
// K-slab ONCE per iter (zero staging redundancy, zero inter-block reuse --
// every input byte is read exactly once from HBM/L3), then 10 waves compute
// the 10 upper-tri 64x64 tiles from that single staging (waves 10-15 stage
// and idle at MFMA). bf16 LDS slab [256][64], 16B-chunk XOR swizzle
// (chunk^(row&7)): stage writes and frag reads both conflict-free.
// R9's proven loop shape: reg-prefetch one iter ahead, 2 barriers/iter.
// ---------------------------------------------------------------------------
__global__ __launch_bounds__(1024, 4) void gram_kernel(
    const float* __restrict__ src, const float* __restrict__ tgt,
    float* __restrict__ Gp, int kshift, int kchunk) {
  const int P = 1 << kshift;
  const int g = blockIdx.x;              // group id; no XCD mapping needed
  const int ch = g >> kshift;            // (no inter-block data sharing at all)
  const int ks = g & (P - 1);
  const int kbase = ks * kchunk;
  const int tid = threadIdx.x;
  const int lane = tid & 63;
  const int wave = tid >> 6;             // 0..15

  __shared__ __attribute__((aligned(16))) ushort S[256 * 64];  // 32 KB bf16 slab

  f32x4 acc[4][4];
#pragma unroll
  for (int m = 0; m < 4; ++m)
#pragma unroll
    for (int n = 0; n < 4; ++n)
      acc[m][n] = (f32x4){0.f, 0.f, 0.f, 0.f};

  // staging geometry: 256 rows x 64 f32 = 4096 16B-chunks; thread handles
  // chunk ids tid, tid+1024, tid+2048, tid+3072 (wave reads 1KB contiguous).
  const float* gptr[4];
  int lw[4];
#pragma unroll
  for (int i = 0; i < 4; ++i) {
    const int id = i * 1024 + tid;
    const int row = id >> 4;             // 0..255
    const int c16 = id & 15;             // f32 chunk within row
    const float* base = (row < 128) ? src + ((size_t)row * NCH + ch) * DIM
                                    : tgt + ((size_t)(row - 128) * NCH + ch) * DIM;
    gptr[i] = base + kbase + c16 * 4;
    const int sch = (c16 >> 1) ^ (row & 7);     // swizzled 16B bf16 chunk
    lw[i] = row * 64 + sch * 8 + (c16 & 1) * 4; // ushort index (8B half-chunk)
  }

  const int ti = g_TI[wave < NTILE ? wave : 0];
  const int tj = g_TJ[wave < NTILE ? wave : 0];

  const int nk = kchunk / BK;  // 8 at P=8

  // prefetch slab 0
  f32x4 v[4];
#pragma unroll
  for (int i = 0; i < 4; ++i) v[i] = *reinterpret_cast<const f32x4*>(gptr[i]);

  for (int it = 0; it < nk; ++it) {
    __syncthreads();  // previous iteration's LDS reads done
    // stage regs -> LDS (cvt_pk, swizzled, conflict-free)
#pragma unroll
    for (int i = 0; i < 4; ++i) {
      uint2 wv;
      wv.x = pack_bf2(v[i].x, v[i].y);
      wv.y = pack_bf2(v[i].z, v[i].w);
      *reinterpret_cast<uint2*>(&S[lw[i]]) = wv;
    }
    // issue next slab's loads; they fly across the MFMA phase
    if (it + 1 < nk) {
      const int ko = (it + 1) * BK;
#pragma unroll
      for (int i = 0; i < 4; ++i)
        v[i] = *reinterpret_cast<const f32x4*>(gptr[i] + ko);
    }
    asm volatile("s_waitcnt lgkmcnt(0)" ::: "memory");  // ds_writes visible
    __builtin_amdgcn_s_barrier();
    asm volatile("" ::: "memory");

    if (wave < NTILE) {
#pragma unroll
      for (int kk = 0; kk < 2; ++kk) {
        const int chunk = kk * 4 + (lane >> 4);  // 16B bf16 chunk 0..7
        bf16x8 a[4], b[4];
#pragma unroll
        for (int m = 0; m < 4; ++m) {
          const int row = ti * 64 + m * 16 + (lane & 15);
          a[m] = *reinterpret_cast<const bf16x8*>(
              &S[row * 64 + (chunk ^ (row & 7)) * 8]);
        }
#pragma unroll
        for (int n = 0; n < 4; ++n) {
          const int row = tj * 64 + n * 16 + (lane & 15);
          b[n] = *reinterpret_cast<const bf16x8*>(
              &S[row * 64 + (chunk ^ (row & 7)) * 8]);
        }
#pragma unroll
        for (int m = 0; m < 4; ++m)
#pragma unroll
          for (int n = 0; n < 4; ++n)
            acc[m][n] = __builtin_amdgcn_mfma_f32_16x16x32_bf16(a[m], b[n],
                                                                acc[m][n], 0, 0, 0);
      }
    }
  }

  // C/D layout (m89): col = lane&15, row = (lane>>4)*4 + reg.
  if (wave < NTILE) {
    float* gp = Gp + (size_t)(ch * P + ks) * (NROW * NROW);
#pragma unroll
    for (int m = 0; m < 4; ++m)
#pragma unroll
      for (int n = 0; n < 4; ++n) {
        const int grow = ti * 64 + m * 16 + ((lane >> 4) << 2);
        const int gcol = tj * 64 + n * 16 + (lane & 15);
#pragma unroll
        for (int j = 0; j < 4; ++j)
          gp[(size_t)(grow + j) * NROW + gcol] = acc[m][n][j];
      }
  }
}

// ---------------------------------------------------------------------------
__device__ __forceinline__ float block_sum256(float v, float* sm) {
#pragma unroll
  for (int o = 32; o > 0; o >>= 1) v += __shfl_down(v, o, 64);
  const int lane = threadIdx.x & 63;
  const int wv = threadIdx.x >> 6;
  if (lane == 0) sm[wv] = v;
  __syncthreads();
  float r = 0.f;
  if (threadIdx.x == 0) r = sm[0] + sm[1] + sm[2] + sm[3];
  __syncthreads();
  return r;  // valid on thread 0
}

// ---------------------------------------------------------------------------
// Fold K-split partials for one (ch,tile) AND produce tile sum + diag trace.
__global__ __launch_bounds__(256) void foldsum_kernel(
    const f32x4* __restrict__ Gp, f32x4* __restrict__ Gf,
    float* __restrict__ sums, int P) {
  const int t = blockIdx.x;
  const int ch = blockIdx.y;
  const int ti = g_TI[t], tj = g_TJ[t];
  const bool isdiag = (ti == tj);
  const int tid = threadIdx.x;
  float s = 0.f, tr = 0.f;
#pragma unroll
  for (int i = 0; i < 4; ++i) {
    const int idx4 = tid * 4 + i;
    const int rrow = idx4 >> 4;       // 0..63
    const int c4 = idx4 & 15;         // 0..15
    const int base_v = (ti * 64 + rrow) * 64 + tj * 16 + c4;
    f32x4 v = Gp[(size_t)(ch * P) * 16384 + base_v];
    for (int p = 1; p < P; ++p) v += Gp[(size_t)(ch * P + p) * 16384 + base_v];
    Gf[(size_t)ch * 16384 + base_v] = v;
    s += (v.x + v.y) + (v.z + v.w);
    if (isdiag) {
      const int cb = c4 * 4;
#pragma unroll
      for (int e = 0; e < 4; ++e)
        if (cb + e == rrow) tr += v[e];
    }
  }
  __shared__ float sm[4];
  float sG = block_sum256(s, sm);
  float sT = block_sum256(tr, sm);
  if (tid == 0) {
    sums[ch * 20 + t] = sG;
    if (isdiag) sums[ch * 20 + 10 + ti] = sT;
  }
}

// ---------------------------------------------------------------------------
// per (tile, ch): w * sign * sum over tile of sum_a exp(-L2/(bw*2^a)).
__global__ __launch_bounds__(256) void mmd_kernel(const float* __restrict__ Gf,
                                                  const float* __restrict__ sums,
                                                  float* __restrict__ partial) {
  const int t = blockIdx.x;
  const int ch = blockIdx.y;
  const int ti = g_TI[t], tj = g_TJ[t];
  const int tid = threadIdx.x;
  const float* gg = Gf + (size_t)ch * (NROW * NROW);

  const float* sc = sums + ch * 20;
  float sumG = 0.f;
#pragma unroll
  for (int k = 0; k < NTILE; ++k)
    sumG += (g_TI[k] == g_TJ[k] ? 1.f : 2.f) * sc[k];
  const float trace = (sc[10] + sc[11]) + (sc[12] + sc[13]);
  const float sumL2 = 2.f * NROW * trace - 2.f * sumG;
  const float bw = sumL2 / (float)(NROW * NROW - NROW) * 0.25f;
  float inv[5];
#pragma unroll
  for (int a = 0; a < 5; ++a) inv[a] = -1.f / (bw * (float)(1 << a));

  __shared__ float dA[64], dB[64];
  if (tid < 64) dA[tid] = gg[(size_t)(ti * 64 + tid) * (NROW + 1)];
  else if (tid < 128) dB[tid - 64] = gg[(size_t)(tj * 64 + (tid - 64)) * (NROW + 1)];
  __syncthreads();

  const int col = tid & 63;
  const int qq = tid >> 6;
  const float dj = dB[col];
  float acc = 0.f;
#pragma unroll 4
  for (int it = 0; it < 16; ++it) {
    const int r = it * 4 + qq;
    const float L2 = dA[r] + dj - 2.f * gg[(size_t)(ti * 64 + r) * NROW + tj * 64 + col];
    float kv = 0.f;
#pragma unroll
    for (int a = 0; a < 5; ++a) kv += __expf(L2 * inv[a]);
    acc += kv;
  }
  __shared__ float sm[4];
  float tot = block_sum256(acc, sm);
  if (tid == 0) {
    float wgt = (ti == tj) ? 1.f : 2.f;                  // off-diag mirror
    float sgn = ((ti >= 2) == (tj >= 2)) ? 1.f : -1.f;   // XX/YY + , XY/YX -
    partial[ch * NTILE + t] = tot * wgt * sgn;
  }
}

__global__ __launch_bounds__(256) void final_kernel(const float* __restrict__ partial,
                                                    float* __restrict__ out) {
  const int tid = threadIdx.x;
  float v = (tid < NCH * NTILE) ? partial[tid] : 0.f;
  __shared__ float sm[4];
  float tot = block_sum256(v, sm);
  if (tid == 0) out[0] = tot * (1.f / (NCH * 128.f * 128.f));
}

// ---------------------------------------------------------------------------
extern "C" void kernel_launch(void* const* d_in, const int* in_sizes, int n_in,
                              void* d_out, int out_size, void* d_ws, size_t ws_size,
                              hipStream_t stream) {
  const float* src = (const float*)d_in[0];
  const float* tgt = (const float*)d_in[1];
  float* out = (float*)d_out;
  const size_t GSZ = (size_t)NROW * NROW;  // 65536

  // P capped at 8 (P=16 blew up foldsum, R10).
  int kshift = 0;
  if (ws_size >= (NCH * 9 * GSZ + 512) * sizeof(float)) kshift = 3;
  else if (ws_size >= (NCH * 5 * GSZ + 512) * sizeof(float)) kshift = 2;
  else if (ws_size >= (NCH * 3 * GSZ + 512) * sizeof(float)) kshift = 1;
  const int P = 1 << kshift;

  float* Gp = (float*)d_ws;
  float* Gf = (P > 1) ? Gp + (size_t)NCH * P * GSZ : Gp;  // P==1: alias
  float* sums = Gf + (size_t)NCH * GSZ;                   // NCH*20
  float* partial = sums + NCH * 20;                       // NCH*10

  gram_kernel<<<dim3(NCH * P), 1024, 0, stream>>>(src, tgt, Gp, kshift,
                                                  DIM >> kshift);
  foldsum_kernel<<<dim3(NTILE, NCH), 256, 0, stream>>>((const f32x4*)Gp,
                                                       (f32x4*)Gf, sums, P);
  mmd_kernel<<<dim3(NTILE, NCH), 256, 0, stream>>>(Gf, sums, partial);
  final_kernel<<<1, 256, 0, stream>>>(partial, out);
}